// Round 8
// baseline (1963.230 us; speedup 1.0000x reference)
//
#include <hip/hip_runtime.h>
#include <hip/hip_cooperative_groups.h>
#include <math.h>

namespace cg = cooperative_groups;

// Problem constants: T=4, B=4, C=2, H=W=128 (HW=16384), E=256, half=128.
#define HW 16384

typedef __attribute__((ext_vector_type(8))) _Float16 half8;
typedef __attribute__((ext_vector_type(4))) float f32x4;

// ---------------------------------------------------------------------------
// k_reorder2: BN-folded 2-plane fp16 split of (w*sc)*4096 into MFMA-A layout:
// plane[kb 4][tap 9][quad 4][oc 256][j 8], ic = kb*32+q*8+j.  (unchanged r7)
// ---------------------------------------------------------------------------
__global__ __launch_bounds__(256)
void k_reorder2(const float* __restrict__ w1, const float* __restrict__ wres,
                const float* __restrict__ g1, const float* __restrict__ b1,
                const float* __restrict__ m1, const float* __restrict__ v1,
                const float* __restrict__ gr, const float* __restrict__ br,
                const float* __restrict__ mr, const float* __restrict__ vr,
                short* __restrict__ whi, short* __restrict__ wmid,
                short* __restrict__ rhi, short* __restrict__ rmid,
                float* __restrict__ bias1, float* __restrict__ biasr) {
    int i = blockIdx.x * 256 + threadIdx.x;
    if (i < 294912) {                 // 256 oc * 128 ic * 9 taps
        int n = i / 1152, rem = i % 1152;
        int ic = rem / 9, tap = rem % 9;
        float sc = g1[n] / sqrtf(v1[n] + 1e-5f);
        float wv = (w1[i] * sc) * 4096.0f;
        _Float16 h = (_Float16)wv;            // RNE
        float r1 = wv - (float)h;
        _Float16 m = (_Float16)r1;
        int kb = ic >> 5, q = (ic >> 3) & 3, j = ic & 7;
        size_t f = ((((size_t)(kb * 9 + tap)) * 4 + q) * 256 + n) * 8 + j;
        whi[f]  = __builtin_bit_cast(short, h);
        wmid[f] = __builtin_bit_cast(short, m);
    }
    if (i < 32768) {                  // 256 oc * 128 ic
        int n = i >> 7, ic = i & 127;
        float sc = gr[n] / sqrtf(vr[n] + 1e-5f);
        float wv = (wres[i] * sc) * 4096.0f;
        _Float16 h = (_Float16)wv;
        float r1 = wv - (float)h;
        _Float16 m = (_Float16)r1;
        int kb = ic >> 5, q = (ic >> 3) & 3, j = ic & 7;
        size_t f = (((size_t)kb * 4 + q) * 256 + n) * 8 + j;
        rhi[f]  = __builtin_bit_cast(short, h);
        rmid[f] = __builtin_bit_cast(short, m);
    }
    if (i < 256) {
        float sc1 = g1[i] / sqrtf(v1[i] + 1e-5f);
        bias1[i] = (b1[i] - m1[i] * sc1) * 4096.0f;
        float scr_ = gr[i] / sqrtf(vr[i] + 1e-5f);
        biasr[i] = (br[i] - mr[i] * scr_) * 4096.0f;
    }
}

// ---------------------------------------------------------------------------
// k_stageA (ROUND 8): ALL of stage A in ONE cooperative launch.
// for t in 0..3:  phase P (= old k_proj, 1024 tiles, 2 per block)
//                 grid.sync()
//                 phase T (= old k_temp, 512 tiles, 1 per block)
//                 grid.sync()
// Replaces 8 dependent kernel launches (each with full drain) by 8 grid
// syncs.  Kernel bodies are byte-identical math to the proven r7 versions;
// k_temp weights staged to LDS once (was 4x).
// 512 blocks x 256 thr; LDS 48K(sl)+9K(wls) = 57K -> exactly 2 blocks/CU,
// 512 co-resident on 256 CUs.
// ---------------------------------------------------------------------------
__global__ __launch_bounds__(256, 2)
void k_stageA(const float* __restrict__ x, const float* __restrict__ wp,
              const float* __restrict__ g0, const float* __restrict__ b0,
              const float* __restrict__ m0, const float* __restrict__ v0,
              const float* __restrict__ wt,
              const float* __restrict__ gt, const float* __restrict__ bt,
              const float* __restrict__ mt_, const float* __restrict__ vt,
              float* __restrict__ vp, float* __restrict__ vtm,
              float* __restrict__ xout, unsigned char* __restrict__ s1c) {
    cg::grid_group grid = cg::this_grid();
    __shared__ __align__(16) unsigned char smem[49152];   // P: xin / T: sl
    __shared__ float wls[2304];
    float* xin = (float*)smem;
    unsigned char* sl = smem;

    const int tid = threadIdx.x;
    const int bid = blockIdx.x;

    for (int i = tid; i < 2304; i += 256) wls[i] = wt[i];   // once, reused 4t

    for (int t = 0; t < 4; ++t) {
        const float* xt = x + (size_t)t * 131072;
        unsigned char* s1t = s1c + (size_t)t * 8388608;
        const int first = (t == 0);

        // ================= phase P: 3x3 conv 2->128 + BN + LIF(vp) ========
        for (int rep = 0; rep < 2; ++rep) {
            const int T = bid + rep * 512;
            const int wtile = T & 3, htile = (T >> 2) & 15, bz = T >> 6;
            const int b = bz >> 2, ocq = bz & 3;
            const int gy0 = htile * 8, gx0 = wtile * 32;

            for (int i = tid; i < 680; i += 256) {
                int ch = i / 340, rem = i % 340;
                int r = rem / 34, c = rem % 34;
                int gy = gy0 - 1 + r, gx = gx0 - 1 + c;
                float val = 0.f;
                if (gy >= 0 && gy < 128 && gx >= 0 && gx < 128) {
                    int idx = ((b * 2 + ch) << 14) + (gy << 7) + gx;
                    val = xt[idx];
                    if (!first) val += xout[idx];
                }
                xin[(ch * 10 + r) * 36 + c] = val;
            }
            __syncthreads();

            const int prow = tid >> 5, pcol = tid & 31;
            float xw[2][3][3];
#pragma unroll
            for (int ch = 0; ch < 2; ++ch)
#pragma unroll
                for (int ky = 0; ky < 3; ++ky)
#pragma unroll
                    for (int kx = 0; kx < 3; ++kx)
                        xw[ch][ky][kx] = xin[(ch * 10 + prow + ky) * 36 + pcol + kx];

            const int pix = ((gy0 + prow) << 7) + gx0 + pcol;
            const int oc_beg = ocq * 32;
            unsigned int pk[8];
#pragma unroll
            for (int k = 0; k < 8; ++k) pk[k] = 0u;
#pragma unroll
            for (int oo = 0; oo < 32; ++oo) {
                const int oc = oc_beg + oo;
                float acc = 0.f;
#pragma unroll
                for (int ch = 0; ch < 2; ++ch)
#pragma unroll
                    for (int ky = 0; ky < 3; ++ky)
#pragma unroll
                        for (int kx = 0; kx < 3; ++kx)
                            acc = fmaf(wp[((oc * 2 + ch) * 3 + ky) * 3 + kx], xw[ch][ky][kx], acc);
                float sc = g0[oc] / sqrtf(v0[oc] + 1e-5f);
                float h  = (acc - m0[oc]) * sc + b0[oc];
                int idx = ((b * 128 + oc) << 14) + pix;
                float v = first ? 0.f : vp[idx];
                v = v + (h - v) * 0.5f;
                bool s = (v >= 1.0f);
                vp[idx] = s ? 0.f : v;
                pk[oo >> 2] |= (s ? 1u : 0u) << ((oo & 3) * 8);
            }
            unsigned char* dst = s1t + ((((size_t)b << 14) + pix) << 7) + oc_beg;
            *(uint4*)dst        = make_uint4(pk[0], pk[1], pk[2], pk[3]);
            *(uint4*)(dst + 16) = make_uint4(pk[4], pk[5], pk[6], pk[7]);
            __syncthreads();   // xin reads done before rep-1 restage
        }
        __threadfence();
        grid.sync();           // s1t complete before phase T reads it

        // ================= phase T: 3x3 conv 128->2 + BN + LIF(vtm) =======
        {
            const int b = bid >> 7, y0 = bid & 127;
            const unsigned char* sb = s1t + ((size_t)b << 21);
#pragma unroll
            for (int r = 0; r < 3; ++r) {
                int gy = y0 - 1 + r;
                bool ok = (gy >= 0 && gy < 128);
                const unsigned char* rowp = sb + ((size_t)gy << 14);
#pragma unroll
                for (int k = 0; k < 4; ++k) {
                    int c = tid + k * 256;              // [0,1024) 16B chunks
                    uint4 d = make_uint4(0u, 0u, 0u, 0u);
                    if (ok) d = *(const uint4*)(rowp + c * 16);
                    int p = c >> 3;
                    int icb0 = (c & 7) * 2;
                    int p0 = p ^ (icb0 & 7);
                    int p1 = p ^ ((icb0 + 1) & 7);
                    *(uint2*)&sl[(((icb0)     * 3 + r) * 128 + p0) * 8] = make_uint2(d.x, d.y);
                    *(uint2*)&sl[(((icb0 + 1) * 3 + r) * 128 + p1) * 8] = make_uint2(d.z, d.w);
                }
            }
            __syncthreads();

            if (tid < 128) {
                const int xc = tid;
                float a0 = 0.f, a1 = 0.f;
#pragma unroll 1
                for (int icb = 0; icb < 16; ++icb) {
                    int sw = icb & 7;
                    const float* w0 = &wls[icb * 72];
                    const float* w1_ = &wls[1152 + icb * 72];
#pragma unroll
                    for (int dy = 0; dy < 3; ++dy) {
#pragma unroll
                        for (int dx = 0; dx < 3; ++dx) {
                            int xx = xc - 1 + dx;
                            if (xx < 0 || xx > 127) continue;
                            uint2 d = *(const uint2*)&sl[((icb * 3 + dy) * 128 + (xx ^ sw)) * 8];
                            int tap = dy * 3 + dx;
#pragma unroll
                            for (int j = 0; j < 4; ++j) {
                                float f0 = (float)((d.x >> (8 * j)) & 0xFFu);
                                float f1 = (float)((d.y >> (8 * j)) & 0xFFu);
                                a0 = fmaf(w0[j * 9 + tap],        f0, a0);
                                a0 = fmaf(w0[(4 + j) * 9 + tap],  f1, a0);
                                a1 = fmaf(w1_[j * 9 + tap],       f0, a1);
                                a1 = fmaf(w1_[(4 + j) * 9 + tap], f1, a1);
                            }
                        }
                    }
                }
#pragma unroll
                for (int oc = 0; oc < 2; ++oc) {
                    float acc = (oc == 0) ? a0 : a1;
                    float sc = gt[oc] / sqrtf(vt[oc] + 1e-5f);
                    float yv = (acc - mt_[oc]) * sc + bt[oc];
                    int idx = ((b * 2 + oc) << 14) + (y0 << 7) + xc;
                    float v = first ? 0.f : vtm[idx];
                    v = v + (yv - v) * 0.5f;
                    bool s = (v >= 1.0f);
                    vtm[idx]  = s ? 0.f : v;
                    xout[idx] = s ? 1.0f : 0.f;
                }
            }
            __syncthreads();   // sl reads done before next t's phase-P smem use
        }
        __threadfence();
        grid.sync();           // xout complete before next t's phase P
    }
}

// ---------------------------------------------------------------------------
// k_fused: UNCHANGED from round 7 (weights=A fp16 2-plane, spikes=B,
// direct stores, 2 barriers/t).
// ---------------------------------------------------------------------------
__global__ __launch_bounds__(256, 3)
void k_fused(const unsigned char* __restrict__ s1c,
             const short* __restrict__ whi, const short* __restrict__ wmid,
             const short* __restrict__ rhi, const short* __restrict__ rmid,
             const float* __restrict__ bias1, const float* __restrict__ biasr,
             float* __restrict__ out) {
    __shared__ __align__(16) char lds[52736];   // 16 icb * 206 entries * 16B

    const int tid = threadIdx.x;
    const int oc0 = blockIdx.x * 64;
    const int yb = blockIdx.y;
    const int b = yb >> 7, ry = (yb >> 2) & 31, cx = yb & 3;
    const int gy0 = ry * 4, gx0 = cx * 32;

    const int w   = tid >> 6, l = tid & 63;
    const int q   = l >> 4,  ln = l & 15;
    const int woc = w >> 1,  wpx = w & 1;

    f32x4 ba[2], brr[2];
#pragma unroll
    for (int mt = 0; mt < 2; ++mt)
#pragma unroll
        for (int rg = 0; rg < 4; ++rg) {
            int oc = oc0 + woc * 32 + mt * 16 + q * 4 + rg;
            ba[mt][rg]  = bias1[oc];
            brr[mt][rg] = biasr[oc];
        }

    const size_t wofs = ((size_t)q * 256 + oc0 + woc * 32 + ln) * 8;

    int pb[4], po[4];
#pragma unroll
    for (int nt = 0; nt < 4; ++nt) {
        int px = wpx * 64 + nt * 16 + ln;
        int prow = px >> 5, pcol = px & 31;
        pb[nt] = prow * 34 + pcol;
        po[nt] = ((gy0 + prow) << 7) + gx0 + pcol;
    }

    float va[4][2][4], vres[4][2][4];
#pragma unroll
    for (int nt = 0; nt < 4; ++nt)
#pragma unroll
        for (int mt = 0; mt < 2; ++mt)
#pragma unroll
            for (int rg = 0; rg < 4; ++rg) { va[nt][mt][rg] = 0.f; vres[nt][mt][rg] = 0.f; }

#pragma unroll 1
    for (int t = 0; t < 4; ++t) {
        const unsigned char* s1t = s1c + (size_t)t * 8388608 + ((size_t)b << 21);

        for (int cc = tid; cc < 3264; cc += 256) {
            int p = cc >> 4, icb = cc & 15;
            int r = p / 34, c = p - r * 34;
            int gy = gy0 - 1 + r, gx = gx0 - 1 + c;
            uint2 d = make_uint2(0u, 0u);
            if (gy >= 0 && gy < 128 && gx >= 0 && gx < 128)
                d = *(const uint2*)(s1t + ((size_t)((gy << 7) + gx) << 7) + icb * 8);
            uint4 pk;                      // fp16 1.0 = 0x3C00
            pk.x = ((d.x & 1u)          | ((d.x & 0x100u) << 8))   * 0x3C00u;
            pk.y = (((d.x >> 16) & 1u)  | ((d.x >> 8) & 0x10000u)) * 0x3C00u;
            pk.z = ((d.y & 1u)          | ((d.y & 0x100u) << 8))   * 0x3C00u;
            pk.w = (((d.y >> 16) & 1u)  | ((d.y >> 8) & 0x10000u)) * 0x3C00u;
            *(uint4*)(lds + (icb * 206 + p) * 16) = pk;
        }
        __syncthreads();

        f32x4 acc[4][2], accr[4][2];
#pragma unroll
        for (int nt = 0; nt < 4; ++nt)
#pragma unroll
            for (int mt = 0; mt < 2; ++mt) { acc[nt][mt] = ba[mt]; accr[nt][mt] = brr[mt]; }

        const short* bh = whi  + wofs;
        const short* bm = wmid + wofs;

#pragma unroll 1
        for (int kb = 0; kb < 4; ++kb) {
            const char* bkb = lds + (size_t)(kb * 4 + q) * 3296;   // 206*16
#pragma unroll
            for (int ky = 0; ky < 3; ++ky) {
#pragma unroll
                for (int kx = 0; kx < 3; ++kx) {
                    half8 B4[4];
#pragma unroll
                    for (int nt = 0; nt < 4; ++nt)
                        B4[nt] = *(const half8*)(bkb + (pb[nt] + ky * 34 + kx) * 16);
                    half8 AH[2], AM[2];
#pragma unroll
                    for (int mt = 0; mt < 2; ++mt) {
                        AH[mt] = *(const half8*)(bh + mt * 128);
                        AM[mt] = *(const half8*)(bm + mt * 128);
                    }
#pragma unroll
                    for (int nt = 0; nt < 4; ++nt)
#pragma unroll
                        for (int mt = 0; mt < 2; ++mt) {
                            acc[nt][mt] = __builtin_amdgcn_mfma_f32_16x16x32_f16(AH[mt], B4[nt], acc[nt][mt], 0, 0, 0);
                            acc[nt][mt] = __builtin_amdgcn_mfma_f32_16x16x32_f16(AM[mt], B4[nt], acc[nt][mt], 0, 0, 0);
                        }
                    if (ky == 1 && kx == 1) {
                        half8 RH[2], RM[2];
#pragma unroll
                        for (int mt = 0; mt < 2; ++mt) {
                            RH[mt] = *(const half8*)(rhi  + wofs + (size_t)kb * 8192 + mt * 128);
                            RM[mt] = *(const half8*)(rmid + wofs + (size_t)kb * 8192 + mt * 128);
                        }
#pragma unroll
                        for (int nt = 0; nt < 4; ++nt)
#pragma unroll
                            for (int mt = 0; mt < 2; ++mt) {
                                accr[nt][mt] = __builtin_amdgcn_mfma_f32_16x16x32_f16(RH[mt], B4[nt], accr[nt][mt], 0, 0, 0);
                                accr[nt][mt] = __builtin_amdgcn_mfma_f32_16x16x32_f16(RM[mt], B4[nt], accr[nt][mt], 0, 0, 0);
                            }
                    }
                    bh += 8192; bm += 8192;
                }
            }
        }
        __syncthreads();

        const float ds_ = 0.000244140625f;   // 2^-12, exact
        const size_t tb = ((size_t)((t * 4 + b) * 256 + oc0)) << 14;
#pragma unroll
        for (int mt = 0; mt < 2; ++mt)
#pragma unroll
            for (int rg = 0; rg < 4; ++rg) {
                const size_t ob = tb + ((size_t)(woc * 32 + mt * 16 + q * 4 + rg) << 14);
#pragma unroll
                for (int nt = 0; nt < 4; ++nt) {
                    float ha = acc[nt][mt][rg] * ds_;
                    float v = va[nt][mt][rg];
                    v = v + (ha - v) * 0.5f;
                    bool s = (v >= 1.0f);
                    va[nt][mt][rg] = s ? 0.f : v;
                    float sa = s ? 1.f : 0.f;

                    float hr = accr[nt][mt][rg] * ds_;
                    float u = vres[nt][mt][rg];
                    u = u + (hr - u) * 0.5f;
                    bool sr_ = (u >= 1.0f);
                    vres[nt][mt][rg] = sr_ ? 0.f : u;

                    out[ob + po[nt]] = sa + (sr_ ? 1.f : 0.f);
                }
            }
    }
}

// ---------------------------------------------------------------------------
// Workspace layout (bytes):
//   s1c    @ 0          33,554,432  (u8 spikes CHANNEL-LAST [T][B][pix][128ic])
//   vp     @ 33,554,432 33,554,432  (LIF state; t=0 skip-read -> NO memset;
//     dead after stage A -> fp16 weight planes overlap it:
//     whi @33,554,432 (589,824), wmid @34,144,256 (589,824),
//     rhi @34,734,080 (65,536), rmid @34,799,616 (65,536),
//     bias1 @34,865,152 (1,024), biasr @34,866,176 (1,024))
//   vtm    @ 67,108,864    524,288  (t=0 skip-read)
//   xout   @ 67,633,152    524,288  (t=0 not read)   total = 68,157,440
// ---------------------------------------------------------------------------
extern "C" void kernel_launch(void* const* d_in, const int* in_sizes, int n_in,
                              void* d_out, int out_size, void* d_ws, size_t ws_size,
                              hipStream_t stream) {
    const float* x      = (const float*)d_in[0];
    const float* w_proj = (const float*)d_in[1];
    const float* g0 = (const float*)d_in[2];
    const float* b0 = (const float*)d_in[3];
    const float* m0 = (const float*)d_in[4];
    const float* v0 = (const float*)d_in[5];
    const float* w_temp = (const float*)d_in[6];
    const float* gt = (const float*)d_in[7];
    const float* bt = (const float*)d_in[8];
    const float* mt = (const float*)d_in[9];
    const float* vt = (const float*)d_in[10];
    const float* w1 = (const float*)d_in[11];
    const float* g1 = (const float*)d_in[12];
    const float* b1 = (const float*)d_in[13];
    const float* m1 = (const float*)d_in[14];
    const float* v1 = (const float*)d_in[15];
    const float* w_res = (const float*)d_in[16];
    const float* gr = (const float*)d_in[17];
    const float* br = (const float*)d_in[18];
    const float* mr = (const float*)d_in[19];
    const float* vr = (const float*)d_in[20];

    char* ws = (char*)d_ws;
    unsigned char* s1c = (unsigned char*)ws;
    float* vp    = (float*)(ws + 33554432);
    short* whi   = (short*)(ws + 33554432);   // overlaps vp (dead after stage A)
    short* wmid  = (short*)(ws + 34144256);
    short* rhi   = (short*)(ws + 34734080);
    short* rmid  = (short*)(ws + 34799616);
    float* bias1 = (float*)(ws + 34865152);
    float* biasr = (float*)(ws + 34866176);
    float* vtm   = (float*)(ws + 67108864);
    float* xout  = (float*)(ws + 67633152);

    // ---- stage A: one cooperative launch (replaces 8 dependent kernels) ----
    void* cargs[] = { (void*)&x, (void*)&w_proj,
                      (void*)&g0, (void*)&b0, (void*)&m0, (void*)&v0,
                      (void*)&w_temp,
                      (void*)&gt, (void*)&bt, (void*)&mt, (void*)&vt,
                      (void*)&vp, (void*)&vtm, (void*)&xout, (void*)&s1c };
    hipLaunchCooperativeKernel((const void*)k_stageA, dim3(512), dim3(256),
                               cargs, 0, stream);

    // weights reorder AFTER stage A (planes overlap the now-dead vp)
    k_reorder2<<<dim3(1152), dim3(256), 0, stream>>>(
        w1, w_res, g1, b1, m1, v1, gr, br, mr, vr,
        whi, wmid, rhi, rmid, bias1, biasr);

    k_fused<<<dim3(4, 512), dim3(256), 0, stream>>>(
        s1c, whi, wmid, rhi, rmid, bias1, biasr, (float*)d_out);
}

// Round 9
// 962.161 us; speedup vs baseline: 2.0404x; 2.0404x over previous
//
#include <hip/hip_runtime.h>
#include <math.h>

// Problem constants: T=4, B=4, C=2, H=W=128 (HW=16384), E=256, half=128.
#define HW 16384

typedef __attribute__((ext_vector_type(8))) _Float16 half8;
typedef __attribute__((ext_vector_type(4))) float f32x4;

// ---------------------------------------------------------------------------
// k_reorder2: BN-folded 2-plane fp16 split of (w*sc)*4096 into MFMA-A layout:
// plane[kb 4][tap 9][quad 4][oc 256][j 8], ic = kb*32+q*8+j.  (r7 proven)
// Planes no longer overlap vp -> this runs FIRST (off the critical tail).
// ---------------------------------------------------------------------------
__global__ __launch_bounds__(256)
void k_reorder2(const float* __restrict__ w1, const float* __restrict__ wres,
                const float* __restrict__ g1, const float* __restrict__ b1,
                const float* __restrict__ m1, const float* __restrict__ v1,
                const float* __restrict__ gr, const float* __restrict__ br,
                const float* __restrict__ mr, const float* __restrict__ vr,
                short* __restrict__ whi, short* __restrict__ wmid,
                short* __restrict__ rhi, short* __restrict__ rmid,
                float* __restrict__ bias1, float* __restrict__ biasr) {
    int i = blockIdx.x * 256 + threadIdx.x;
    if (i < 294912) {                 // 256 oc * 128 ic * 9 taps
        int n = i / 1152, rem = i % 1152;
        int ic = rem / 9, tap = rem % 9;
        float sc = g1[n] / sqrtf(v1[n] + 1e-5f);
        float wv = (w1[i] * sc) * 4096.0f;
        _Float16 h = (_Float16)wv;            // RNE
        float r1 = wv - (float)h;
        _Float16 m = (_Float16)r1;
        int kb = ic >> 5, q = (ic >> 3) & 3, j = ic & 7;
        size_t f = ((((size_t)(kb * 9 + tap)) * 4 + q) * 256 + n) * 8 + j;
        whi[f]  = __builtin_bit_cast(short, h);
        wmid[f] = __builtin_bit_cast(short, m);
    }
    if (i < 32768) {                  // 256 oc * 128 ic
        int n = i >> 7, ic = i & 127;
        float sc = gr[n] / sqrtf(vr[n] + 1e-5f);
        float wv = (wres[i] * sc) * 4096.0f;
        _Float16 h = (_Float16)wv;
        float r1 = wv - (float)h;
        _Float16 m = (_Float16)r1;
        int kb = ic >> 5, q = (ic >> 3) & 3, j = ic & 7;
        size_t f = (((size_t)kb * 4 + q) * 256 + n) * 8 + j;
        rhi[f]  = __builtin_bit_cast(short, h);
        rmid[f] = __builtin_bit_cast(short, m);
    }
    if (i < 256) {
        float sc1 = g1[i] / sqrtf(v1[i] + 1e-5f);
        bias1[i] = (b1[i] - m1[i] * sc1) * 4096.0f;
        float scr_ = gr[i] / sqrtf(vr[i] + 1e-5f);
        biasr[i] = (br[i] - mr[i] * scr_) * 4096.0f;
    }
}

// ---------------------------------------------------------------------------
// k_proj (per t): x_in = x[t] + (first ? 0 : x_out);  3x3 conv 2->128 + BN +
// LIF(vp, skip-read at t=0).  Spikes CHANNEL-LAST u8.  (r7 exact)
// grid (4,16,16), block 256.
// ---------------------------------------------------------------------------
__global__ __launch_bounds__(256)
void k_proj(const float* __restrict__ xt, const float* __restrict__ xout,
            const float* __restrict__ wp,
            const float* __restrict__ g, const float* __restrict__ bb,
            const float* __restrict__ mm, const float* __restrict__ vv,
            float* __restrict__ vp, unsigned char* __restrict__ s1t, int first) {
    __shared__ float xin[2 * 10 * 36];
    const int tid = threadIdx.x;
    const int b   = blockIdx.z >> 2;
    const int ocq = blockIdx.z & 3;
    const int gy0 = blockIdx.y * 8, gx0 = blockIdx.x * 32;

    for (int i = tid; i < 680; i += 256) {
        int ch = i / 340, rem = i % 340;
        int r = rem / 34, c = rem % 34;
        int gy = gy0 - 1 + r, gx = gx0 - 1 + c;
        float val = 0.f;
        if (gy >= 0 && gy < 128 && gx >= 0 && gx < 128) {
            int idx = ((b * 2 + ch) << 14) + (gy << 7) + gx;
            val = xt[idx];
            if (!first) val += xout[idx];
        }
        xin[(ch * 10 + r) * 36 + c] = val;
    }
    __syncthreads();

    const int prow = tid >> 5, pcol = tid & 31;
    float xw[2][3][3];
#pragma unroll
    for (int ch = 0; ch < 2; ++ch)
#pragma unroll
        for (int ky = 0; ky < 3; ++ky)
#pragma unroll
            for (int kx = 0; kx < 3; ++kx)
                xw[ch][ky][kx] = xin[(ch * 10 + prow + ky) * 36 + pcol + kx];

    const int pix = ((gy0 + prow) << 7) + gx0 + pcol;
    const int oc_beg = ocq * 32;
    unsigned int pk[8];
#pragma unroll
    for (int k = 0; k < 8; ++k) pk[k] = 0u;
#pragma unroll
    for (int oo = 0; oo < 32; ++oo) {
        const int oc = oc_beg + oo;
        float acc = 0.f;
#pragma unroll
        for (int ch = 0; ch < 2; ++ch)
#pragma unroll
            for (int ky = 0; ky < 3; ++ky)
#pragma unroll
                for (int kx = 0; kx < 3; ++kx)
                    acc = fmaf(wp[((oc * 2 + ch) * 3 + ky) * 3 + kx], xw[ch][ky][kx], acc);
        float sc = g[oc] / sqrtf(vv[oc] + 1e-5f);
        float h  = (acc - mm[oc]) * sc + bb[oc];
        int idx = ((b * 128 + oc) << 14) + pix;
        float v = first ? 0.f : vp[idx];
        v = v + (h - v) * 0.5f;
        bool s = (v >= 1.0f);
        vp[idx] = s ? 0.f : v;
        pk[oo >> 2] |= (s ? 1u : 0u) << ((oo & 3) * 8);
    }
    unsigned char* dst = s1t + ((((size_t)b << 14) + pix) << 7) + oc_beg;
    *(uint4*)dst        = make_uint4(pk[0], pk[1], pk[2], pk[3]);
    *(uint4*)(dst + 16) = make_uint4(pk[4], pk[5], pk[6], pk[7]);
}

// ---------------------------------------------------------------------------
// k_temp (per t, ROUND 9): 3x3 conv 128->2 + BN + LIF(vtm).  Split-K over ic:
// 256-thread block = 128 px x 2 ic-halves (icb 0-7 / 8-15), LDS pair-reduce.
// Doubles waves/CU 4->8 (r7 ran 128-thr blocks = latency-starved) and halves
// per-thread LDS-read chain.  grid (128 rows, B), block 256.
// ---------------------------------------------------------------------------
__global__ __launch_bounds__(256)
void k_temp(const unsigned char* __restrict__ s1t, const float* __restrict__ wt,
            const float* __restrict__ g, const float* __restrict__ bb,
            const float* __restrict__ mm, const float* __restrict__ vv,
            float* __restrict__ vtm, float* __restrict__ xout, int first) {
    __shared__ unsigned char sl[49152];   // [icb 16][r 3][p 128] * 8B
    __shared__ float wls[2304];
    __shared__ float red[256];            // partials: [oc 2][px 128]
    const int tid = threadIdx.x;
    const int b   = blockIdx.y;
    const int y0  = blockIdx.x;

    for (int i = tid; i < 2304; i += 256) wls[i] = wt[i];

    const unsigned char* sb = s1t + ((size_t)b << 21);
#pragma unroll
    for (int r = 0; r < 3; ++r) {
        int gy = y0 - 1 + r;
        bool ok = (gy >= 0 && gy < 128);
        const unsigned char* rowp = sb + ((size_t)gy << 14);
#pragma unroll
        for (int k = 0; k < 4; ++k) {
            int c = tid + k * 256;              // [0,1024) 16B chunks
            uint4 d = make_uint4(0u, 0u, 0u, 0u);
            if (ok) d = *(const uint4*)(rowp + c * 16);
            int p = c >> 3;
            int icb0 = (c & 7) * 2;
            int p0 = p ^ (icb0 & 7);
            int p1 = p ^ ((icb0 + 1) & 7);
            *(uint2*)&sl[(((icb0)     * 3 + r) * 128 + p0) * 8] = make_uint2(d.x, d.y);
            *(uint2*)&sl[(((icb0 + 1) * 3 + r) * 128 + p1) * 8] = make_uint2(d.z, d.w);
        }
    }
    __syncthreads();

    const int x = tid & 127, hf = tid >> 7;
    float a0 = 0.f, a1 = 0.f;
#pragma unroll 1
    for (int ii = 0; ii < 8; ++ii) {
        const int icb = hf * 8 + ii;
        int sw = icb & 7;
        const float* w0 = &wls[icb * 72];
        const float* w1_ = &wls[1152 + icb * 72];
#pragma unroll
        for (int dy = 0; dy < 3; ++dy) {
#pragma unroll
            for (int dx = 0; dx < 3; ++dx) {
                int xx = x - 1 + dx;
                if (xx < 0 || xx > 127) continue;
                uint2 d = *(const uint2*)&sl[((icb * 3 + dy) * 128 + (xx ^ sw)) * 8];
                int tap = dy * 3 + dx;
#pragma unroll
                for (int j = 0; j < 4; ++j) {
                    float f0 = (float)((d.x >> (8 * j)) & 0xFFu);
                    float f1 = (float)((d.y >> (8 * j)) & 0xFFu);
                    a0 = fmaf(w0[j * 9 + tap],        f0, a0);
                    a0 = fmaf(w0[(4 + j) * 9 + tap],  f1, a0);
                    a1 = fmaf(w1_[j * 9 + tap],       f0, a1);
                    a1 = fmaf(w1_[(4 + j) * 9 + tap], f1, a1);
                }
            }
        }
    }
    if (hf) { red[x] = a0; red[128 + x] = a1; }
    __syncthreads();
    if (!hf) {
        a0 += red[x]; a1 += red[128 + x];
#pragma unroll
        for (int oc = 0; oc < 2; ++oc) {
            float acc = (oc == 0) ? a0 : a1;
            float sc = g[oc] / sqrtf(vv[oc] + 1e-5f);
            float yv = (acc - mm[oc]) * sc + bb[oc];
            int idx = ((b * 2 + oc) << 14) + (y0 << 7) + x;
            float v = first ? 0.f : vtm[idx];
            v = v + (yv - v) * 0.5f;
            bool s = (v >= 1.0f);
            vtm[idx]  = s ? 0.f : v;
            xout[idx] = s ? 1.0f : 0.f;
        }
    }
}

// ---------------------------------------------------------------------------
// k_fused (ROUND 9): r7 structure + explicit one-tap-ahead A-operand
// prefetch (the per-tap L2 loads fed MFMAs with no pipelining: VGPR=84 shows
// the compiler never hoisted them).  Same MFMA order -> bit-identical.
// Final-step prefetch overruns whi/wmid into the adjacent ws arrays — a
// harmless in-bounds read, result unused.
// grid (4 oc-tiles, 512 px-tiles), block 256 = 4 waves.
// ---------------------------------------------------------------------------
__global__ __launch_bounds__(256, 3)
void k_fused(const unsigned char* __restrict__ s1c,
             const short* __restrict__ whi, const short* __restrict__ wmid,
             const short* __restrict__ rhi, const short* __restrict__ rmid,
             const float* __restrict__ bias1, const float* __restrict__ biasr,
             float* __restrict__ out) {
    __shared__ __align__(16) char lds[52736];   // 16 icb * 206 entries * 16B

    const int tid = threadIdx.x;
    const int oc0 = blockIdx.x * 64;
    const int yb = blockIdx.y;
    const int b = yb >> 7, ry = (yb >> 2) & 31, cx = yb & 3;
    const int gy0 = ry * 4, gx0 = cx * 32;

    const int w   = tid >> 6, l = tid & 63;
    const int q   = l >> 4,  ln = l & 15;
    const int woc = w >> 1,  wpx = w & 1;

    f32x4 ba[2], brr[2];
#pragma unroll
    for (int mt = 0; mt < 2; ++mt)
#pragma unroll
        for (int rg = 0; rg < 4; ++rg) {
            int oc = oc0 + woc * 32 + mt * 16 + q * 4 + rg;
            ba[mt][rg]  = bias1[oc];
            brr[mt][rg] = biasr[oc];
        }

    const size_t wofs = ((size_t)q * 256 + oc0 + woc * 32 + ln) * 8;

    int pb[4], po[4];
#pragma unroll
    for (int nt = 0; nt < 4; ++nt) {
        int px = wpx * 64 + nt * 16 + ln;
        int prow = px >> 5, pcol = px & 31;
        pb[nt] = prow * 34 + pcol;
        po[nt] = ((gy0 + prow) << 7) + gx0 + pcol;
    }

    float va[4][2][4], vres[4][2][4];
#pragma unroll
    for (int nt = 0; nt < 4; ++nt)
#pragma unroll
        for (int mt = 0; mt < 2; ++mt)
#pragma unroll
            for (int rg = 0; rg < 4; ++rg) { va[nt][mt][rg] = 0.f; vres[nt][mt][rg] = 0.f; }

#pragma unroll 1
    for (int t = 0; t < 4; ++t) {
        const unsigned char* s1t = s1c + (size_t)t * 8388608 + ((size_t)b << 21);

        // ---- stage spike window: [icb 16][6 rows x 34 cols] 8-ic fp16 ----
        for (int cc = tid; cc < 3264; cc += 256) {
            int p = cc >> 4, icb = cc & 15;
            int r = p / 34, c = p - r * 34;
            int gy = gy0 - 1 + r, gx = gx0 - 1 + c;
            uint2 d = make_uint2(0u, 0u);
            if (gy >= 0 && gy < 128 && gx >= 0 && gx < 128)
                d = *(const uint2*)(s1t + ((size_t)((gy << 7) + gx) << 7) + icb * 8);
            uint4 pk;                      // fp16 1.0 = 0x3C00
            pk.x = ((d.x & 1u)          | ((d.x & 0x100u) << 8))   * 0x3C00u;
            pk.y = (((d.x >> 16) & 1u)  | ((d.x >> 8) & 0x10000u)) * 0x3C00u;
            pk.z = ((d.y & 1u)          | ((d.y & 0x100u) << 8))   * 0x3C00u;
            pk.w = (((d.y >> 16) & 1u)  | ((d.y >> 8) & 0x10000u)) * 0x3C00u;
            *(uint4*)(lds + (icb * 206 + p) * 16) = pk;
        }
        __syncthreads();

        f32x4 acc[4][2], accr[4][2];
#pragma unroll
        for (int nt = 0; nt < 4; ++nt)
#pragma unroll
            for (int mt = 0; mt < 2; ++mt) { acc[nt][mt] = ba[mt]; accr[nt][mt] = brr[mt]; }

        const short* bh = whi  + wofs;
        const short* bm = wmid + wofs;

        // prime the A-prefetch registers with tap 0
        half8 pAH[2], pAM[2];
#pragma unroll
        for (int mt = 0; mt < 2; ++mt) {
            pAH[mt] = *(const half8*)(bh + mt * 128);
            pAM[mt] = *(const half8*)(bm + mt * 128);
        }

#pragma unroll 1
        for (int kb = 0; kb < 4; ++kb) {
            const char* bkb = lds + (size_t)(kb * 4 + q) * 3296;   // 206*16
#pragma unroll
            for (int ky = 0; ky < 3; ++ky) {
#pragma unroll
                for (int kx = 0; kx < 3; ++kx) {
                    half8 AH[2], AM[2];
#pragma unroll
                    for (int mt = 0; mt < 2; ++mt) { AH[mt] = pAH[mt]; AM[mt] = pAM[mt]; }
                    bh += 8192; bm += 8192;
#pragma unroll
                    for (int mt = 0; mt < 2; ++mt) {   // prefetch next tap
                        pAH[mt] = *(const half8*)(bh + mt * 128);
                        pAM[mt] = *(const half8*)(bm + mt * 128);
                    }
                    half8 B4[4];
#pragma unroll
                    for (int nt = 0; nt < 4; ++nt)
                        B4[nt] = *(const half8*)(bkb + (pb[nt] + ky * 34 + kx) * 16);
#pragma unroll
                    for (int nt = 0; nt < 4; ++nt)
#pragma unroll
                        for (int mt = 0; mt < 2; ++mt) {
                            acc[nt][mt] = __builtin_amdgcn_mfma_f32_16x16x32_f16(AH[mt], B4[nt], acc[nt][mt], 0, 0, 0);
                            acc[nt][mt] = __builtin_amdgcn_mfma_f32_16x16x32_f16(AM[mt], B4[nt], acc[nt][mt], 0, 0, 0);
                        }
                    if (ky == 1 && kx == 1) {   // 1x1 res conv on the center tap
                        half8 RH[2], RM[2];
#pragma unroll
                        for (int mt = 0; mt < 2; ++mt) {
                            RH[mt] = *(const half8*)(rhi  + wofs + (size_t)kb * 8192 + mt * 128);
                            RM[mt] = *(const half8*)(rmid + wofs + (size_t)kb * 8192 + mt * 128);
                        }
#pragma unroll
                        for (int nt = 0; nt < 4; ++nt)
#pragma unroll
                            for (int mt = 0; mt < 2; ++mt) {
                                accr[nt][mt] = __builtin_amdgcn_mfma_f32_16x16x32_f16(RH[mt], B4[nt], accr[nt][mt], 0, 0, 0);
                                accr[nt][mt] = __builtin_amdgcn_mfma_f32_16x16x32_f16(RM[mt], B4[nt], accr[nt][mt], 0, 0, 0);
                            }
                    }
                }
            }
        }
        __syncthreads();   // all LDS reads done; next t may restage

        const float ds_ = 0.000244140625f;   // 2^-12, exact
        const size_t tb = ((size_t)((t * 4 + b) * 256 + oc0)) << 14;
#pragma unroll
        for (int mt = 0; mt < 2; ++mt)
#pragma unroll
            for (int rg = 0; rg < 4; ++rg) {
                const size_t ob = tb + ((size_t)(woc * 32 + mt * 16 + q * 4 + rg) << 14);
#pragma unroll
                for (int nt = 0; nt < 4; ++nt) {
                    float ha = acc[nt][mt][rg] * ds_;
                    float v = va[nt][mt][rg];
                    v = v + (ha - v) * 0.5f;
                    bool s = (v >= 1.0f);
                    va[nt][mt][rg] = s ? 0.f : v;
                    float sa = s ? 1.f : 0.f;

                    float hr = accr[nt][mt][rg] * ds_;
                    float u = vres[nt][mt][rg];
                    u = u + (hr - u) * 0.5f;
                    bool sr_ = (u >= 1.0f);
                    vres[nt][mt][rg] = sr_ ? 0.f : u;

                    out[ob + po[nt]] = sa + (sr_ ? 1.f : 0.f);
                }
            }
    }
}

// ---------------------------------------------------------------------------
// Workspace layout (bytes):
//   s1c    @ 0          33,554,432  (u8 spikes CHANNEL-LAST [T][B][pix][128ic])
//   vp     @ 33,554,432 33,554,432  (LIF state; t=0 skip-read -> no memset)
//   vtm    @ 67,108,864    524,288  (t=0 skip-read)
//   xout   @ 67,633,152    524,288  (t=0 not read)
//   whi    @ 68,157,440    589,824  (fp16 planes — NO vp overlap; reorder
//   wmid   @ 68,747,264    589,824   runs first, off the critical tail)
//   rhi    @ 69,337,088     65,536
//   rmid   @ 69,402,624     65,536
//   bias1  @ 69,468,160      1,024
//   biasr  @ 69,469,184      1,024   total = 69,470,208 (~= round-1's 69.5MB)
// ---------------------------------------------------------------------------
extern "C" void kernel_launch(void* const* d_in, const int* in_sizes, int n_in,
                              void* d_out, int out_size, void* d_ws, size_t ws_size,
                              hipStream_t stream) {
    const float* x      = (const float*)d_in[0];
    const float* w_proj = (const float*)d_in[1];
    const float* g0 = (const float*)d_in[2];
    const float* b0 = (const float*)d_in[3];
    const float* m0 = (const float*)d_in[4];
    const float* v0 = (const float*)d_in[5];
    const float* w_temp = (const float*)d_in[6];
    const float* gt = (const float*)d_in[7];
    const float* bt = (const float*)d_in[8];
    const float* mt = (const float*)d_in[9];
    const float* vt = (const float*)d_in[10];
    const float* w1 = (const float*)d_in[11];
    const float* g1 = (const float*)d_in[12];
    const float* b1 = (const float*)d_in[13];
    const float* m1 = (const float*)d_in[14];
    const float* v1 = (const float*)d_in[15];
    const float* w_res = (const float*)d_in[16];
    const float* gr = (const float*)d_in[17];
    const float* br = (const float*)d_in[18];
    const float* mr = (const float*)d_in[19];
    const float* vr = (const float*)d_in[20];

    char* ws = (char*)d_ws;
    unsigned char* s1c = (unsigned char*)ws;
    float* vp    = (float*)(ws + 33554432);
    float* vtm   = (float*)(ws + 67108864);
    float* xout  = (float*)(ws + 67633152);
    short* whi   = (short*)(ws + 68157440);
    short* wmid  = (short*)(ws + 68747264);
    short* rhi   = (short*)(ws + 69337088);
    short* rmid  = (short*)(ws + 69402624);
    float* bias1 = (float*)(ws + 69468160);
    float* biasr = (float*)(ws + 69469184);

    // weight reorder first: independent of stage A, off the critical tail
    k_reorder2<<<dim3(1152), dim3(256), 0, stream>>>(
        w1, w_res, g1, b1, m1, v1, gr, br, mr, vr,
        whi, wmid, rhi, rmid, bias1, biasr);

    for (int t = 0; t < 4; ++t) {
        const float* xt = x + (size_t)t * 131072;
        unsigned char* s1t = s1c + (size_t)t * 8388608;
        k_proj<<<dim3(4, 16, 16), dim3(256), 0, stream>>>(
            xt, xout, w_proj, g0, b0, m0, v0, vp, s1t, t == 0);
        k_temp<<<dim3(128, 4), dim3(256), 0, stream>>>(
            s1t, w_temp, gt, bt, mt, vt, vtm, xout, t == 0);
    }

    k_fused<<<dim3(4, 512), dim3(256), 0, stream>>>(
        s1c, whi, wmid, rhi, rmid, bias1, biasr, (float*)d_out);
}